// Round 3
// baseline (221.667 us; speedup 1.0000x reference)
//
#include <hip/hip_runtime.h>
#include <hip/hip_bf16.h>
#include <math.h>

#define BDIM 4
#define SLEN 4096
#define DDIM 1024
#define MROWS (BDIM*SLEN)      // 16384
#define KDIM DDIM              // 1024
#define NCHUNK 64
#define CLEN (SLEN/NCHUNK)     // 64
#define NCH (BDIM*DDIM)        // 4096

typedef __bf16 bf16;
typedef __bf16 bf16x8 __attribute__((ext_vector_type(8)));
typedef float f32x4 __attribute__((ext_vector_type(4)));

__device__ __forceinline__ void gload_lds16(const void* g, void* l) {
  __builtin_amdgcn_global_load_lds(
      (const __attribute__((address_space(1))) unsigned int*)g,
      (__attribute__((address_space(3))) unsigned int*)l, 16, 0, 0);
}

// ---------------- cast f32 -> bf16, 8 elems/thread ----------------
__global__ void cast_bf16_kernel(const float* __restrict__ in, bf16* __restrict__ out, int n8) {
  int i = blockIdx.x * blockDim.x + threadIdx.x;
  if (i >= n8) return;
  const float4* p = (const float4*)in;
  float4 v0 = p[2*i], v1 = p[2*i+1];
  bf16x8 o;
  o[0] = (bf16)v0.x; o[1] = (bf16)v0.y; o[2] = (bf16)v0.z; o[3] = (bf16)v0.w;
  o[4] = (bf16)v1.x; o[5] = (bf16)v1.y; o[6] = (bf16)v1.z; o[7] = (bf16)v1.w;
  ((bf16x8*)out)[i] = o;
}

// ---------------- klam[h] = -C * softplus(-Lam[h]) ----------------
__global__ void klam_kernel(const float* __restrict__ Lam, float* __restrict__ klam) {
  int h = blockIdx.x * blockDim.x + threadIdx.x;
  if (h < DDIM) klam[h] = -8.0f * log1pf(__expf(-Lam[h]));
}

// ---------------- dual-weight GEMM + gate epilogue ----------------
// Block tile 128(M) x 64(N), BK=32, 4 waves of 64x32-dual each.
// LDS tiles stored in FRAGMENT ORDER (pre-swizzled global source, m173):
//   16B granule for (row, kgran) lives at byte (row>>4)*1024 + kgran*256 + (row&15)*16
// so every MFMA fragment read is base + lane*16 -> zero bank conflicts.
__global__ __launch_bounds__(256, 3) void gemm_gates_kernel(
    const bf16* __restrict__ xb, const bf16* __restrict__ wab, const bf16* __restrict__ wxb,
    const float* __restrict__ ba, const float* __restrict__ bx,
    const float* __restrict__ klam, float* __restrict__ Aarr, float* __restrict__ Barr)
{
  __shared__ bf16 Xs[128*32];   // 8 KB
  __shared__ bf16 Was[64*32];   // 4 KB
  __shared__ bf16 Wxs[64*32];   // 4 KB

  const int tid  = threadIdx.x;
  const int wave = tid >> 6, lane = tid & 63;
  const int wm = wave >> 1, wn = wave & 1;       // M split 2x64, N split 2x32

  // XCD-bijective swizzle: 2048 blocks, 8 XCDs, 256 each.
  const int orig  = blockIdx.x;
  const int newid = (orig & 7) * 256 + (orig >> 3);
  const int m0 = (newid >> 4) * 128;
  const int h0 = (newid & 15) * 64;

  f32x4 accA[4][2], accX[4][2];
  #pragma unroll
  for (int i = 0; i < 4; i++)
    #pragma unroll
    for (int j = 0; j < 2; j++) { accA[i][j] = (f32x4)0.0f; accX[i][j] = (f32x4)0.0f; }

  // staging decomposition: LDS slot tid holds (row = blk*16 + sr, kgran = sj)
  const int sblk = tid >> 6;          // 16-row block (0..3)
  const int sj   = (tid >> 4) & 3;    // k-granule (0..3), 8 elems each
  const int sr   = tid & 15;          // row within 16-row block
  const int grow = sblk * 16 + sr;    // row within 64-row slab
  const int gk   = sj * 8;            // k elem offset
  char* xsBase = (char*)Xs;
  char* waBase = (char*)Was;
  char* wxBase = (char*)Wxs;

  for (int kt = 0; kt < KDIM/32; ++kt) {
    const int k0 = kt * 32;
    #pragma unroll
    for (int i = 0; i < 2; ++i)
      gload_lds16(xb + (size_t)(m0 + i*64 + grow) * KDIM + k0 + gk,
                  xsBase + i*4096 + tid*16);
    gload_lds16(wab + (size_t)(h0 + grow) * KDIM + k0 + gk, waBase + tid*16);
    gload_lds16(wxb + (size_t)(h0 + grow) * KDIM + k0 + gk, wxBase + tid*16);
    __syncthreads();

    bf16x8 af[4], bfa[2], bfx[2];
    #pragma unroll
    for (int mi = 0; mi < 4; mi++)
      af[mi] = *(const bf16x8*)(xsBase + (wm*4 + mi)*1024 + lane*16);
    #pragma unroll
    for (int ni = 0; ni < 2; ni++) {
      bfa[ni] = *(const bf16x8*)(waBase + (wn*2 + ni)*1024 + lane*16);
      bfx[ni] = *(const bf16x8*)(wxBase + (wn*2 + ni)*1024 + lane*16);
    }
    #pragma unroll
    for (int mi = 0; mi < 4; mi++)
      #pragma unroll
      for (int ni = 0; ni < 2; ni++) {
        accA[mi][ni] = __builtin_amdgcn_mfma_f32_16x16x32_bf16(af[mi], bfa[ni], accA[mi][ni], 0, 0, 0);
        accX[mi][ni] = __builtin_amdgcn_mfma_f32_16x16x32_bf16(af[mi], bfx[ni], accX[mi][ni], 0, 0, 0);
      }
    __syncthreads();
  }

  // epilogue: C/D layout col = lane&15 (h), row = (lane>>4)*4 + j (m)
  #pragma unroll
  for (int mi = 0; mi < 4; mi++) {
    #pragma unroll
    for (int ni = 0; ni < 2; ni++) {
      const int h  = h0 + wn*32 + ni*16 + (lane & 15);
      const int mb = m0 + wm*64 + mi*16 + ((lane >> 4) << 2);
      const float bah = ba[h], bxh = bx[h], kl = klam[h];
      #pragma unroll
      for (int j = 0; j < 4; j++) {
        const int m = mb + j;
        const float ga = accA[mi][ni][j] + bah;
        const float gx = accX[mi][ni][j] + bxh;
        const float rt = 1.0f / (1.0f + __expf(-ga));
        const float it = 1.0f / (1.0f + __expf(-gx));
        const float a  = __expf(kl * rt);
        const float xv = (float)xb[(size_t)m * DDIM + h];
        const float bb = sqrtf(fmaxf(1.0f - a*a, 0.0f)) * (it * xv);
        Aarr[(size_t)m * DDIM + h] = a;
        Barr[(size_t)m * DDIM + h] = bb;
      }
    }
  }
}

// ---------------- chunked scan: phase 1 (per-chunk summaries) ----------------
__global__ void scan1_kernel(const float* __restrict__ Aarr, const float* __restrict__ Barr,
                             float* __restrict__ sA, float* __restrict__ sB) {
  const int ch = blockIdx.x * 256 + threadIdx.x;   // 0..4095 = b*1024 + d
  const int c  = blockIdx.y;                       // chunk
  const int b  = ch >> 10, d = ch & 1023;
  size_t idx = ((size_t)b * SLEN + (size_t)c * CLEN) * DDIM + d;
  float pa = 1.0f, h = 0.0f;
  #pragma unroll 4
  for (int s = 0; s < CLEN; ++s) {
    const float a  = Aarr[idx];
    const float bb = Barr[idx];
    h  = fmaf(a, h, bb);
    pa *= a;
    idx += DDIM;
  }
  sA[c * NCH + ch] = pa;
  sB[c * NCH + ch] = h;
}

// ---------------- phase 2: sequential prefix over chunks ----------------
__global__ void scan2_kernel(const float* __restrict__ sA, const float* __restrict__ sB,
                             float* __restrict__ Hin) {
  const int ch = blockIdx.x * 256 + threadIdx.x;
  float h = 0.0f;
  for (int c = 0; c < NCHUNK; ++c) {
    Hin[c * NCH + ch] = h;
    h = fmaf(sA[c * NCH + ch], h, sB[c * NCH + ch]);
  }
}

// ---------------- phase 3: apply (in place over Barr == d_out) ----------------
__global__ void scan3_kernel(const float* __restrict__ Aarr, const float* __restrict__ Hin,
                             float* __restrict__ y) {
  const int ch = blockIdx.x * 256 + threadIdx.x;
  const int c  = blockIdx.y;
  const int b  = ch >> 10, d = ch & 1023;
  size_t idx = ((size_t)b * SLEN + (size_t)c * CLEN) * DDIM + d;
  float h = Hin[c * NCH + ch];
  #pragma unroll 4
  for (int s = 0; s < CLEN; ++s) {
    const float a  = Aarr[idx];
    const float bb = y[idx];
    h = fmaf(a, h, bb);
    y[idx] = h;
    idx += DDIM;
  }
}

extern "C" void kernel_launch(void* const* d_in, const int* in_sizes, int n_in,
                              void* d_out, int out_size, void* d_ws, size_t ws_size,
                              hipStream_t stream) {
  const float* x   = (const float*)d_in[0];
  const float* Wa  = (const float*)d_in[1];
  const float* Wx  = (const float*)d_in[2];
  const float* ba  = (const float*)d_in[3];
  const float* bx  = (const float*)d_in[4];
  const float* Lam = (const float*)d_in[5];
  float* y = (float*)d_out;

  // workspace layout (bytes): needs 108,007,424 total
  if (ws_size < 108007424ULL) return;  // insufficient scratch; fail cleanly
  char* ws = (char*)d_ws;
  float* Aarr = (float*)(ws);                    // 64 MB: decay a
  bf16*  xb   = (bf16*)(ws + 67108864);          // 32 MB: x in bf16
  bf16*  wab  = (bf16*)(ws + 100663296);         //  2 MB
  bf16*  wxb  = (bf16*)(ws + 102760448);         //  2 MB
  float* klam = (float*)(ws + 104857600);        //  4 KB
  float* sA   = (float*)(ws + 104861696);        //  1 MB
  float* sB   = (float*)(ws + 105910272);        //  1 MB
  float* Hin  = (float*)(ws + 106958848);        //  1 MB
  float* Barr = y;                               // b lives in d_out, transformed in place

  cast_bf16_kernel<<<(MROWS*DDIM/8)/256, 256, 0, stream>>>(x,  xb,  MROWS*DDIM/8);
  cast_bf16_kernel<<<(DDIM*DDIM/8)/256, 256, 0, stream>>>(Wa, wab, DDIM*DDIM/8);
  cast_bf16_kernel<<<(DDIM*DDIM/8)/256, 256, 0, stream>>>(Wx, wxb, DDIM*DDIM/8);
  klam_kernel<<<DDIM/256, 256, 0, stream>>>(Lam, klam);

  // 2048 blocks: (M/128) * (N/64) = 128 * 16
  gemm_gates_kernel<<<2048, 256, 0, stream>>>(xb, wab, wxb, ba, bx, klam, Aarr, Barr);

  dim3 sgrid(NCH/256, NCHUNK);
  scan1_kernel<<<sgrid, 256, 0, stream>>>(Aarr, Barr, sA, sB);
  scan2_kernel<<<NCH/256, 256, 0, stream>>>(sA, sB, Hin);
  scan3_kernel<<<sgrid, 256, 0, stream>>>(Aarr, Hin, y);
}

// Round 4
// 176.736 us; speedup vs baseline: 1.2542x; 1.2542x over previous
//
#include <hip/hip_runtime.h>
#include <hip/hip_bf16.h>
#include <math.h>

#define BDIM 4
#define SLEN 4096
#define DDIM 1024
#define MROWS (BDIM*SLEN)      // 16384
#define KDIM DDIM              // 1024
#define NCHUNK 64
#define CLEN (SLEN/NCHUNK)     // 64
#define NCH (BDIM*DDIM)        // 4096

typedef __bf16 bf16;
typedef __bf16 bf16x8 __attribute__((ext_vector_type(8)));
typedef float f32x4 __attribute__((ext_vector_type(4)));

__device__ __forceinline__ void gload_lds16(const void* g, void* l) {
  __builtin_amdgcn_global_load_lds(
      (const __attribute__((address_space(1))) unsigned int*)g,
      (__attribute__((address_space(3))) unsigned int*)l, 16, 0, 0);
}

// ---------------- cast f32 -> bf16, 8 elems/thread ----------------
__global__ void cast_bf16_kernel(const float* __restrict__ in, bf16* __restrict__ out, int n8) {
  int i = blockIdx.x * blockDim.x + threadIdx.x;
  if (i >= n8) return;
  const float4* p = (const float4*)in;
  float4 v0 = p[2*i], v1 = p[2*i+1];
  bf16x8 o;
  o[0] = (bf16)v0.x; o[1] = (bf16)v0.y; o[2] = (bf16)v0.z; o[3] = (bf16)v0.w;
  o[4] = (bf16)v1.x; o[5] = (bf16)v1.y; o[6] = (bf16)v1.z; o[7] = (bf16)v1.w;
  ((bf16x8*)out)[i] = o;
}

// ---------------- klam[h] = -C * softplus(-Lam[h]) ----------------
__global__ void klam_kernel(const float* __restrict__ Lam, float* __restrict__ klam) {
  int h = blockIdx.x * blockDim.x + threadIdx.x;
  if (h < DDIM) klam[h] = -8.0f * log1pf(__expf(-Lam[h]));
}

// ---------------- dual-weight GEMM + gate epilogue ----------------
// Block tile 128(M) x 64(N), BK=32, 4 waves of 64x32-dual each.
// LDS granule swizzle (both-sides, rule #21): granule kg of row r stored at
// slot j = kg ^ ((r>>2)&3) within the row's 64B span.
//   - global side: each 4-lane cluster reads one contiguous 64B segment
//     (internally permuted) -> full VMEM coalescing, same as R2.
//   - read side: frag addr = blk*1024 + (l&15)*64 + ((l>>4)^((l&15)>>2))*16;
//     per 16-lane phase all 16 addrs distinct mod 256B -> conflict-free.
__global__ __launch_bounds__(256, 3) void gemm_gates_kernel(
    const bf16* __restrict__ xb, const bf16* __restrict__ wab, const bf16* __restrict__ wxb,
    const float* __restrict__ ba, const float* __restrict__ bx,
    const float* __restrict__ klam, float* __restrict__ Aarr, float* __restrict__ Barr)
{
  __shared__ bf16 Xs[128*32];   // 8 KB
  __shared__ bf16 Was[64*32];   // 4 KB
  __shared__ bf16 Wxs[64*32];   // 4 KB

  const int tid  = threadIdx.x;
  const int wave = tid >> 6, lane = tid & 63;
  const int wm = wave >> 1, wn = wave & 1;       // M split 2x64, N split 2x32

  // XCD-bijective swizzle: 2048 blocks, 8 XCDs, 256 each.
  const int orig  = blockIdx.x;
  const int newid = (orig & 7) * 256 + (orig >> 3);
  const int m0 = (newid >> 4) * 128;
  const int h0 = (newid & 15) * 64;

  f32x4 accA[4][2], accX[4][2];
  #pragma unroll
  for (int i = 0; i < 4; i++)
    #pragma unroll
    for (int j = 0; j < 2; j++) { accA[i][j] = (f32x4)0.0f; accX[i][j] = (f32x4)0.0f; }

  // staging: lane tid -> LDS slot tid*16. Slot (row = tid>>2, j = tid&3)
  // holds global granule kg = j ^ ((row>>2)&3) = (tid&3) ^ ((tid>>4)&3).
  const int srow = tid >> 2;                          // row within 64-row slab
  const int skc  = (((tid & 3) ^ ((tid >> 4) & 3))) * 8;   // swizzled k-granule
  // fragment-read per-lane offset within a 16-row block (1024B)
  const int lroff = (lane & 15) * 64 + (((lane >> 4) ^ ((lane & 15) >> 2)) * 16);

  char* xsBase = (char*)Xs;
  char* waBase = (char*)Was;
  char* wxBase = (char*)Wxs;

  for (int kt = 0; kt < KDIM/32; ++kt) {
    const int k0 = kt * 32;
    #pragma unroll
    for (int i = 0; i < 2; ++i)
      gload_lds16(xb + (size_t)(m0 + i*64 + srow) * KDIM + k0 + skc,
                  xsBase + i*4096 + tid*16);
    gload_lds16(wab + (size_t)(h0 + srow) * KDIM + k0 + skc, waBase + tid*16);
    gload_lds16(wxb + (size_t)(h0 + srow) * KDIM + k0 + skc, wxBase + tid*16);
    __syncthreads();

    bf16x8 af[4], bfa[2], bfx[2];
    #pragma unroll
    for (int mi = 0; mi < 4; mi++)
      af[mi] = *(const bf16x8*)(xsBase + (wm*4 + mi)*1024 + lroff);
    #pragma unroll
    for (int ni = 0; ni < 2; ni++) {
      bfa[ni] = *(const bf16x8*)(waBase + (wn*2 + ni)*1024 + lroff);
      bfx[ni] = *(const bf16x8*)(wxBase + (wn*2 + ni)*1024 + lroff);
    }
    #pragma unroll
    for (int mi = 0; mi < 4; mi++)
      #pragma unroll
      for (int ni = 0; ni < 2; ni++) {
        accA[mi][ni] = __builtin_amdgcn_mfma_f32_16x16x32_bf16(af[mi], bfa[ni], accA[mi][ni], 0, 0, 0);
        accX[mi][ni] = __builtin_amdgcn_mfma_f32_16x16x32_bf16(af[mi], bfx[ni], accX[mi][ni], 0, 0, 0);
      }
    __syncthreads();
  }

  // epilogue: C/D layout col = lane&15 (h), row = (lane>>4)*4 + j (m)
  #pragma unroll
  for (int mi = 0; mi < 4; mi++) {
    #pragma unroll
    for (int ni = 0; ni < 2; ni++) {
      const int h  = h0 + wn*32 + ni*16 + (lane & 15);
      const int mb = m0 + wm*64 + mi*16 + ((lane >> 4) << 2);
      const float bah = ba[h], bxh = bx[h], kl = klam[h];
      #pragma unroll
      for (int j = 0; j < 4; j++) {
        const int m = mb + j;
        const float ga = accA[mi][ni][j] + bah;
        const float gx = accX[mi][ni][j] + bxh;
        const float rt = 1.0f / (1.0f + __expf(-ga));
        const float it = 1.0f / (1.0f + __expf(-gx));
        const float a  = __expf(kl * rt);
        const float xv = (float)xb[(size_t)m * DDIM + h];
        const float bb = sqrtf(fmaxf(1.0f - a*a, 0.0f)) * (it * xv);
        Aarr[(size_t)m * DDIM + h] = a;
        Barr[(size_t)m * DDIM + h] = bb;
      }
    }
  }
}

// ---------------- chunked scan: phase 1 (per-chunk summaries) ----------------
__global__ void scan1_kernel(const float* __restrict__ Aarr, const float* __restrict__ Barr,
                             float* __restrict__ sA, float* __restrict__ sB) {
  const int ch = blockIdx.x * 256 + threadIdx.x;   // 0..4095 = b*1024 + d
  const int c  = blockIdx.y;                       // chunk
  const int b  = ch >> 10, d = ch & 1023;
  size_t idx = ((size_t)b * SLEN + (size_t)c * CLEN) * DDIM + d;
  float pa = 1.0f, h = 0.0f;
  #pragma unroll 4
  for (int s = 0; s < CLEN; ++s) {
    const float a  = Aarr[idx];
    const float bb = Barr[idx];
    h  = fmaf(a, h, bb);
    pa *= a;
    idx += DDIM;
  }
  sA[c * NCH + ch] = pa;
  sB[c * NCH + ch] = h;
}

// ---------------- phase 2: sequential prefix over chunks ----------------
__global__ void scan2_kernel(const float* __restrict__ sA, const float* __restrict__ sB,
                             float* __restrict__ Hin) {
  const int ch = blockIdx.x * 256 + threadIdx.x;
  float h = 0.0f;
  for (int c = 0; c < NCHUNK; ++c) {
    Hin[c * NCH + ch] = h;
    h = fmaf(sA[c * NCH + ch], h, sB[c * NCH + ch]);
  }
}

// ---------------- phase 3: apply (in place over Barr == d_out) ----------------
__global__ void scan3_kernel(const float* __restrict__ Aarr, const float* __restrict__ Hin,
                             float* __restrict__ y) {
  const int ch = blockIdx.x * 256 + threadIdx.x;
  const int c  = blockIdx.y;
  const int b  = ch >> 10, d = ch & 1023;
  size_t idx = ((size_t)b * SLEN + (size_t)c * CLEN) * DDIM + d;
  float h = Hin[c * NCH + ch];
  #pragma unroll 4
  for (int s = 0; s < CLEN; ++s) {
    const float a  = Aarr[idx];
    const float bb = y[idx];
    h = fmaf(a, h, bb);
    y[idx] = h;
    idx += DDIM;
  }
}

extern "C" void kernel_launch(void* const* d_in, const int* in_sizes, int n_in,
                              void* d_out, int out_size, void* d_ws, size_t ws_size,
                              hipStream_t stream) {
  const float* x   = (const float*)d_in[0];
  const float* Wa  = (const float*)d_in[1];
  const float* Wx  = (const float*)d_in[2];
  const float* ba  = (const float*)d_in[3];
  const float* bx  = (const float*)d_in[4];
  const float* Lam = (const float*)d_in[5];
  float* y = (float*)d_out;

  // workspace layout (bytes): needs 108,007,424 total
  if (ws_size < 108007424ULL) return;  // insufficient scratch; fail cleanly
  char* ws = (char*)d_ws;
  float* Aarr = (float*)(ws);                    // 64 MB: decay a
  bf16*  xb   = (bf16*)(ws + 67108864);          // 32 MB: x in bf16
  bf16*  wab  = (bf16*)(ws + 100663296);         //  2 MB
  bf16*  wxb  = (bf16*)(ws + 102760448);         //  2 MB
  float* klam = (float*)(ws + 104857600);        //  4 KB
  float* sA   = (float*)(ws + 104861696);        //  1 MB
  float* sB   = (float*)(ws + 105910272);        //  1 MB
  float* Hin  = (float*)(ws + 106958848);        //  1 MB
  float* Barr = y;                               // b lives in d_out, transformed in place

  cast_bf16_kernel<<<(MROWS*DDIM/8)/256, 256, 0, stream>>>(x,  xb,  MROWS*DDIM/8);
  cast_bf16_kernel<<<(DDIM*DDIM/8)/256, 256, 0, stream>>>(Wa, wab, DDIM*DDIM/8);
  cast_bf16_kernel<<<(DDIM*DDIM/8)/256, 256, 0, stream>>>(Wx, wxb, DDIM*DDIM/8);
  klam_kernel<<<DDIM/256, 256, 0, stream>>>(Lam, klam);

  // 2048 blocks: (M/128) * (N/64) = 128 * 16
  gemm_gates_kernel<<<2048, 256, 0, stream>>>(xb, wab, wxb, ba, bx, klam, Aarr, Barr);

  dim3 sgrid(NCH/256, NCHUNK);
  scan1_kernel<<<sgrid, 256, 0, stream>>>(Aarr, Barr, sA, sB);
  scan2_kernel<<<NCH/256, 256, 0, stream>>>(sA, sB, Hin);
  scan3_kernel<<<sgrid, 256, 0, stream>>>(Aarr, Hin, y);
}